// Round 7
// baseline (894.352 us; speedup 1.0000x reference)
//
#include <hip/hip_runtime.h>
#include <math.h>

#define NTOT 32000000   // 4*128*250*250

typedef __attribute__((ext_vector_type(8))) short bf8_t;   // 8 bf16 (4 VGPRs)
typedef __attribute__((ext_vector_type(4))) float f4_t;    // MFMA accumulator

__device__ __forceinline__ float fast_tanh(float t) {
    return 1.0f - 2.0f / (1.0f + __expf(2.0f * t));
}
__device__ __forceinline__ float gelu_f(float v) {
    return 0.5f * v * (1.0f + fast_tanh(0.7978845608028654f * (v + 0.044715f * v * v * v)));
}
__device__ __forceinline__ float sigmoid_f(float v) {
    return 1.0f / (1.0f + __expf(-v));
}
__device__ __forceinline__ unsigned short f2bf(float f) {
    unsigned u = __float_as_uint(f);
    u = (u + 0x7FFFu + ((u >> 16) & 1u)) >> 16;
    return (unsigned short)u;
}
__device__ __forceinline__ float bf2f(unsigned short u) {
    return __uint_as_float(((unsigned)u) << 16);
}
// packed f32x2 -> bf16x2 (RTNE, same bits as f2bf): D[15:0]=cvt(a), D[31:16]=cvt(b)
__device__ __forceinline__ unsigned cvtpk(float a, float b) {
    unsigned r;
    asm("v_cvt_pk_bf16_f32 %0, %1, %2" : "=v"(r) : "v"(a), "v"(b));
    return r;
}
__device__ __forceinline__ unsigned swz(unsigned a) {   // flat-byte XOR swizzle (mlp ZL)
    return a ^ (((a >> 9) & 7u) << 4);
}
// row XOR swizzle: ONLY valid for row pitches that are multiples of 128 B
__device__ __forceinline__ unsigned fxor(int row) {
    return ((unsigned)(row & 1) << 6) ^ ((unsigned)((row >> 1) & 7) << 4);
}

// ---------- S4D discretization: store dt*Re(A), dt*Im(A), 2*C' ----------
__global__ void wc_kernel(const float* __restrict__ log_dt, const float* __restrict__ logA_re,
                          const float* __restrict__ A_im, const float* __restrict__ C_re,
                          const float* __restrict__ C_im, float* __restrict__ wC) {
    int t = blockIdx.x * 256 + threadIdx.x;
    if (t >= 128 * 32) return;
    int h = t >> 5, m = t & 31;
    float dt  = expf(log_dt[h]);
    float are = -expf(logA_re[t]);
    float aim = A_im[t];
    float er  = expf(dt * are);
    float wr  = er * cosf(dt * aim);
    float wi  = er * sinf(dt * aim);
    float e1r = wr - 1.0f, e1i = wi;
    float inv = 1.0f / (are * are + aim * aim);
    float qr  = (e1r * are + e1i * aim) * inv;
    float qi  = (e1i * are - e1r * aim) * inv;
    float cre = C_re[t], cim = C_im[t];
    wC[h * 128 + m]      = dt * are;
    wC[h * 128 + 32 + m] = dt * aim;
    wC[h * 128 + 64 + m] = 2.0f * (cre * qr - cim * qi);
    wC[h * 128 + 96 + m] = 2.0f * (cre * qi + cim * qr);
}

// ---------- conv kernel taps: kern[h][l] = 2*Re(sum_m C'_m exp(dtA_m*l)) + D[h]*(l==0) ----------
__global__ void kern_kernel(const float* __restrict__ wC, const float* __restrict__ Dv,
                            float* __restrict__ kern) {
    int h = blockIdx.x, l = threadIdx.x;
    const float* wc = wC + (h << 7);
    float acc = 0.0f;
    if (l < 250) {
        float fl = (float)l;
#pragma unroll 1
        for (int m = 0; m < 32; ++m) {
            float er  = expf(wc[m] * fl);
            float ang = wc[32 + m] * fl;
            float sv, cv;
            sincosf(ang, &sv, &cv);
            acc += er * (wc[64 + m] * cv - wc[96 + m] * sv);
        }
        if (l == 0) acc += Dv[h];
    }
    kern[(h << 8) + l] = acc;
}

// ---------- Toeplitz A-fragments (hi/lo bf16) per (h, diag16, lane) ----------
__global__ void frag_kernel(const float* __restrict__ kern, unsigned short* __restrict__ fragH,
                            unsigned short* __restrict__ fragL) {
    int h = blockIdx.x, d16 = blockIdx.y, lane = threadIdx.x;
    int lid = lane & 15, q = lane >> 4;
    const float* kh = kern + (h << 8);
    bf8_t vh, vl;
#pragma unroll
    for (int j = 0; j < 8; ++j) {
        int idx = d16 * 16 + lid - 8 * q - j;
        float v = (idx >= 0) ? kh[idx] : 0.0f;
        unsigned short hb = f2bf(v);
        vh[j] = (short)hb;
        vl[j] = (short)f2bf(v - bf2f(hb));
    }
    long off = ((long)((h << 4) + d16) * 64 + lane) * 8;
    *(bf8_t*)(fragH + off) = vh;
    *(bf8_t*)(fragL + off) = vl;
}

// ---------- weight fp32 -> bf16 ----------
__global__ void cvtw_kernel(const float* __restrict__ ow, const float* __restrict__ lw,
                            unsigned short* __restrict__ owbf, unsigned short* __restrict__ lwbf) {
    int t = blockIdx.x * 256 + threadIdx.x;
    if (t < 32768) owbf[t] = f2bf(ow[t]);
    else if (t < 49152) lwbf[t - 32768] = f2bf(lw[t - 32768]);
}

// ---------- causal S4D conv as Toeplitz MFMA GEMM (bf16x3 ~ fp32) + GELU -> bf16 Y ----------
// STAGE-ONCE structure: full 64x256 hi AND lo staged up front (64 KB LDS, 2 blocks/CU),
// then the whole 8-chunk MFMA sweep runs with ZERO barriers (was 17 barriers/block -> 3).
// cvt_pk_bf16_f32 (hw RTNE, bit-identical to f2bf) for all hi/lo splits.
__global__ __launch_bounds__(256, 2)
void conv_kernel(const float* __restrict__ in, unsigned short* __restrict__ Y,
                 const unsigned short* __restrict__ fragH, const unsigned short* __restrict__ fragL,
                 int inter) {
    __shared__ unsigned short Bhi[64 * 256];   // [seq][k] hi bf16, 512B rows, fxor-swizzled
    __shared__ unsigned short Blo[64 * 256];   // [seq][k] lo bf16, 512B rows, fxor-swizzled
    const int tid = threadIdx.x;
    const int lane = tid & 63, wave = tid >> 6;
    const int lid = lane & 15, quad = lane >> 4;
    const int a = wave >> 1, p = wave & 1;
    const int s0 = blockIdx.x * 64;
    const int h = blockIdx.y, b = blockIdx.z;
    const float* src = in + (long)(b * 128 + h) * 62500;
    char* BhiB = (char*)Bhi;
    char* BloB = (char*)Blo;
    const int q8 = tid >> 5;            // 0..7 (k-group within chunk)
    const int spL = (tid & 31) << 1;    // 0..62 (even seq row)

    // ---- stage EVERYTHING (no barriers; loads independent -> deep MLP) ----
    if (!inter) {
#pragma unroll
        for (int c = 0; c < 8; ++c) {
            float2 pf[4];
#pragma unroll
            for (int it = 0; it < 4; ++it) {
                int k = (c << 5) + q8 * 4 + it;
                bool v = (k < 250) && (s0 + spL < 250);
                pf[it] = v ? *(const float2*)(src + (long)k * 250 + s0 + spL)
                           : make_float2(0.0f, 0.0f);
            }
            unsigned hx0 = cvtpk(pf[0].x, pf[1].x);
            unsigned hx1 = cvtpk(pf[2].x, pf[3].x);
            unsigned hy0 = cvtpk(pf[0].y, pf[1].y);
            unsigned hy1 = cvtpk(pf[2].y, pf[3].y);
            unsigned lx0 = cvtpk(pf[0].x - __uint_as_float(hx0 << 16),
                                 pf[1].x - __uint_as_float(hx0 & 0xFFFF0000u));
            unsigned lx1 = cvtpk(pf[2].x - __uint_as_float(hx1 << 16),
                                 pf[3].x - __uint_as_float(hx1 & 0xFFFF0000u));
            unsigned ly0 = cvtpk(pf[0].y - __uint_as_float(hy0 << 16),
                                 pf[1].y - __uint_as_float(hy0 & 0xFFFF0000u));
            unsigned ly1 = cvtpk(pf[2].y - __uint_as_float(hy1 << 16),
                                 pf[3].y - __uint_as_float(hy1 & 0xFFFF0000u));
            unsigned colB = (unsigned)((c << 6) + (q8 << 3));
            unsigned a0 = ((unsigned)(spL * 512) + colB) ^ fxor(spL);
            unsigned a1 = ((unsigned)((spL + 1) * 512) + colB) ^ fxor(spL + 1);
            *(uint2*)(BhiB + a0) = make_uint2(hx0, hx1);
            *(uint2*)(BhiB + a1) = make_uint2(hy0, hy1);
            *(uint2*)(BloB + a0) = make_uint2(lx0, lx1);
            *(uint2*)(BloB + a1) = make_uint2(ly0, ly1);
        }
    } else {
#pragma unroll
        for (int c = 0; c < 8; ++c) {
#pragma unroll
            for (int it = 0; it < 4; ++it) {
                int i = tid + it * 256;
                int sq = i >> 4;
                int tt = (i & 15) << 1;
                int t = (c << 5) + tt;
                bool v = (s0 + sq < 250) && (t < 250);
                float2 pf = v ? *(const float2*)(src + (long)(s0 + sq) * 250 + t)
                              : make_float2(0.0f, 0.0f);
                unsigned hp = cvtpk(pf.x, pf.y);
                unsigned lp = cvtpk(pf.x - __uint_as_float(hp << 16),
                                    pf.y - __uint_as_float(hp & 0xFFFF0000u));
                unsigned b0 = ((unsigned)(sq * 512 + t * 2)) ^ fxor(sq);
                *(unsigned*)(BhiB + b0) = hp;
                *(unsigned*)(BloB + b0) = lp;
            }
        }
    }
    __syncthreads();   // staging visible to all waves

    // ---- full MFMA sweep, ZERO barriers ----
    f4_t acc[4][4];
#pragma unroll
    for (int rt = 0; rt < 4; ++rt)
#pragma unroll
        for (int ct = 0; ct < 4; ++ct) acc[rt][ct] = (f4_t)0.0f;
#pragma unroll 2
    for (int c = 0; c < 8; ++c) {
        bf8_t bh[4], bl[4];
#pragma unroll
        for (int ct = 0; ct < 4; ++ct) {
            int row = ct * 16 + lid;
            unsigned byteB = (((unsigned)(row * 512 + c * 64 + quad * 16)) ^ fxor(row));
            bh[ct] = *(const bf8_t*)(BhiB + byteB);
            bl[ct] = *(const bf8_t*)(BloB + byteB);
        }
#pragma unroll
        for (int rt = 0; rt < 4; ++rt) {
            int n = 2 * rt + a - c;     // diag index; active iff n >= 0 (causality)
            if (n >= 0) {
                long fo = ((long)((h << 4) + 2 * n + p) * 64 + lane) * 8;
                bf8_t fh = *(const bf8_t*)(fragH + fo);
                bf8_t fl = *(const bf8_t*)(fragL + fo);
#pragma unroll
                for (int ct = 0; ct < 4; ++ct) {
                    acc[rt][ct] = __builtin_amdgcn_mfma_f32_16x16x32_bf16(fh, bh[ct], acc[rt][ct], 0, 0, 0);
                    acc[rt][ct] = __builtin_amdgcn_mfma_f32_16x16x32_bf16(fh, bl[ct], acc[rt][ct], 0, 0, 0);
                    acc[rt][ct] = __builtin_amdgcn_mfma_f32_16x16x32_bf16(fl, bh[ct], acc[rt][ct], 0, 0, 0);
                }
            }
        }
    }
    __syncthreads();   // all B-reads done before epilogue overwrites Bhi
    // epilogue: gelu(acc) -> Bhi[seq][l] bf16 (packed 8B writes)
#pragma unroll
    for (int rt = 0; rt < 4; ++rt) {
        const int l0 = rt * 64 + wave * 16 + quad * 4;
#pragma unroll
        for (int ct = 0; ct < 4; ++ct) {
            const int sq = ct * 16 + lid;
            unsigned lo = cvtpk(gelu_f(acc[rt][ct][0]), gelu_f(acc[rt][ct][1]));
            unsigned hi = cvtpk(gelu_f(acc[rt][ct][2]), gelu_f(acc[rt][ct][3]));
            unsigned byteO = ((unsigned)(sq * 512 + l0 * 2)) ^ fxor(sq);
            *(uint2*)(BhiB + byteO) = make_uint2(lo, hi);
        }
    }
    __syncthreads();
    // coalesced copy-out: Y[(b*250+s0+sq)*128 + h][l], 250 bf16 = 125 u32 per row
    unsigned int* Yg = (unsigned int*)Y + ((long)(b * 250 + s0) * 128 + h) * 125;
#pragma unroll 1
    for (int i = tid; i < 8192; i += 256) {
        int sq = i >> 7, e = i & 127;
        if (e < 125 && s0 + sq < 250) {
            unsigned v = *(unsigned*)(BhiB + (((unsigned)(sq * 512 + e * 4)) ^ fxor(sq)));
            Yg[(long)sq * 16000 + e] = v;
        }
    }
}

// ---------- fused MLP (half-seq blocks): GEMM1+GLU -> flat LDS -> GEMM2 -> V + GN partials ----------
// Exact split: flat rows [0,125) use h<64, rows [125,250) use h>=64 (125*128 == 64*250).
__global__ __launch_bounds__(256, 3)
void mlp_kernel(const unsigned short* __restrict__ Ybf, const unsigned short* __restrict__ owbf,
                const float* __restrict__ ob, const unsigned short* __restrict__ lwbf,
                const float* __restrict__ lb, float* __restrict__ V, float* __restrict__ part) {
    __shared__ unsigned short ZL[16000];     // 32 KB: local flat bf16 (h'*250+l)*2 ^ swz
    __shared__ unsigned short Yt[32 * 128];  // chunk transpose [l(32)][h(128)], 256B rows, fxor'd
    const int tid = threadIdx.x;
    const int lane = tid & 63, wave = tid >> 6;
    const int lid = lane & 15, quad = lane >> 4;
    const int seq = blockIdx.x, hf = blockIdx.y;
    const unsigned short* Ys = Ybf + (long)seq * 32000;
    char* YtB = (char*)Yt;
    char* ZLB = (char*)ZL;

    const int tA = 4 * hf + wave;        // z1 tile
    const int tB = 8 + 4 * hf + wave;    // z2 tile
    bf8_t wf[4][2];
#pragma unroll
    for (int c = 0; c < 4; ++c) {
        wf[c][0] = *(const bf8_t*)(owbf + (tA * 16 + lid) * 128 + c * 32 + quad * 8);
        wf[c][1] = *(const bf8_t*)(owbf + (tB * 16 + lid) * 128 + c * 32 + quad * 8);
    }
    float ob1[4], ob2[4];
#pragma unroll
    for (int reg = 0; reg < 4; ++reg) {
        int hp = wave * 16 + quad * 4 + reg;    // local h' in [0,64)
        ob1[reg] = ob[64 * hf + hp];
        ob2[reg] = ob[128 + 64 * hf + hp];
    }

    unsigned int pf[8];
    auto loadc = [&](int l0) {
#pragma unroll
        for (int it = 0; it < 8; ++it) {
            int i = tid + it * 256;
            int hh = i >> 4;
            int l = l0 + (i & 15) * 2;
            pf[it] = (l < 250) ? *(const unsigned int*)(Ys + hh * 250 + l) : 0u;
        }
    };
    auto storec = [&]() {
#pragma unroll
        for (int it = 0; it < 8; ++it) {
            int i = tid + it * 256;
            int hh = i >> 4;
            int l2 = (i & 15) * 2;
            unsigned a0 = ((unsigned)(l2 * 256 + hh * 2)) ^ fxor(l2);
            unsigned a1 = ((unsigned)((l2 + 1) * 256 + hh * 2)) ^ fxor(l2 + 1);
            *(unsigned short*)(YtB + a0) = (unsigned short)(pf[it] & 0xFFFF);
            *(unsigned short*)(YtB + a1) = (unsigned short)(pf[it] >> 16);
        }
    };

    loadc(0);
#pragma unroll 1
    for (int ch = 0; ch < 8; ++ch) {
        __syncthreads();
        storec();
        __syncthreads();
        if (ch < 7) loadc((ch + 1) * 32);
        f4_t acc[2][2];
#pragma unroll
        for (int pp = 0; pp < 2; ++pp)
#pragma unroll
            for (int jj = 0; jj < 2; ++jj) acc[pp][jj] = (f4_t)0.0f;
#pragma unroll
        for (int c = 0; c < 4; ++c) {
            bf8_t bfr[2];
#pragma unroll
            for (int jj = 0; jj < 2; ++jj) {
                int row = jj * 16 + lid;
                bfr[jj] = *(const bf8_t*)(YtB + (((unsigned)(row * 256 + c * 64 + quad * 16)) ^ fxor(row)));
            }
#pragma unroll
            for (int pp = 0; pp < 2; ++pp)
#pragma unroll
                for (int jj = 0; jj < 2; ++jj)
                    acc[pp][jj] = __builtin_amdgcn_mfma_f32_16x16x32_bf16(wf[c][pp], bfr[jj], acc[pp][jj], 0, 0, 0);
        }
        const int lbase = ch * 32;
#pragma unroll
        for (int reg = 0; reg < 4; ++reg) {
            int hp = wave * 16 + quad * 4 + reg;
#pragma unroll
            for (int jj = 0; jj < 2; ++jj) {
                int l = lbase + jj * 16 + lid;
                if (l < 250) {
                    float z1 = acc[0][jj][reg] + ob1[reg];
                    float z2 = acc[1][jj][reg] + ob2[reg];
                    unsigned aB = swz((unsigned)(hp * 250 + l) * 2u);
                    *(unsigned short*)(ZLB + aB) = f2bf(z1 * sigmoid_f(z2));
                }
            }
        }
    }
    __syncthreads();

    // GEMM2: 4 waves x 32 local flat rows (125 valid)
    f4_t acc2[2][8];
#pragma unroll
    for (int mt = 0; mt < 2; ++mt)
#pragma unroll
        for (int nt = 0; nt < 8; ++nt) acc2[mt][nt] = (f4_t)0.0f;
    const int jl0 = wave * 32;
#pragma unroll
    for (int c = 0; c < 4; ++c) {
        bf8_t af[2];
#pragma unroll
        for (int mt = 0; mt < 2; ++mt) {
            int jl = jl0 + mt * 16 + lid;
            if (jl > 124) jl = 124;
            af[mt] = *(const bf8_t*)(ZLB + swz((unsigned)(jl * 128 + c * 32 + quad * 8) * 2u));
        }
#pragma unroll
        for (int nt = 0; nt < 8; ++nt) {
            bf8_t bfr = *(const bf8_t*)(lwbf + (nt * 16 + lid) * 128 + c * 32 + quad * 8);
#pragma unroll
            for (int mt = 0; mt < 2; ++mt)
                acc2[mt][nt] = __builtin_amdgcn_mfma_f32_16x16x32_bf16(af[mt], bfr, acc2[mt][nt], 0, 0, 0);
        }
    }
    float s = 0.0f, q = 0.0f;
    float* Vs = V + (long)seq * 32000 + hf * 16000;
#pragma unroll
    for (int nt = 0; nt < 8; ++nt) {
        int o = nt * 16 + lid;
        float bb = lb[o];
#pragma unroll
        for (int mt = 0; mt < 2; ++mt)
#pragma unroll
            for (int reg = 0; reg < 4; ++reg) {
                int jlr = jl0 + mt * 16 + quad * 4 + reg;
                if (jlr < 125) {
                    float v = acc2[mt][nt][reg] + bb;
                    Vs[jlr * 128 + o] = v;
                    s += v;
                    q += v * v;
                }
            }
    }
    __syncthreads();
    float* red = (float*)Yt;
    red[tid] = s;
    red[256 + tid] = q;
    __syncthreads();
    for (int st = 128; st > 0; st >>= 1) {
        if (tid < st) {
            red[tid] += red[tid + st];
            red[256 + tid] += red[256 + tid + st];
        }
        __syncthreads();
    }
    if (tid == 0) {
        part[(seq * 2 + hf) * 2]     = red[0];
        part[(seq * 2 + hf) * 2 + 1] = red[256];
    }
}

// ---------- reduce per-(seq,half) partials (500 per batch) -> mean, rstd ----------
__global__ void stats_final_kernel(const float* __restrict__ part, float* __restrict__ stats) {
    __shared__ double ssum[256], ssq[256];
    const int b = blockIdx.x;
    double s = 0.0, q = 0.0;
    for (int i = threadIdx.x; i < 500; i += 256) {
        s += (double)part[(b * 500 + i) * 2];
        q += (double)part[(b * 500 + i) * 2 + 1];
    }
    ssum[threadIdx.x] = s; ssq[threadIdx.x] = q;
    __syncthreads();
    for (int st = 128; st > 0; st >>= 1) {
        if (threadIdx.x < st) {
            ssum[threadIdx.x] += ssum[threadIdx.x + st];
            ssq[threadIdx.x]  += ssq[threadIdx.x + st];
        }
        __syncthreads();
    }
    if (threadIdx.x == 0) {
        double mu = ssum[0] / 8000000.0;
        double var = ssq[0] / 8000000.0 - mu * mu;
        stats[b * 2] = (float)mu;
        stats[b * 2 + 1] = (float)(1.0 / sqrt(var + 1e-8));
    }
}

// ---------- intra finalize: transpose-back + GN affine + residual x -> out[B,N,K,S] ----------
__global__ void intra_fin_kernel(const float* __restrict__ f, const float* __restrict__ x,
                                 const float* __restrict__ stats, const float* __restrict__ gg,
                                 const float* __restrict__ gb, float* __restrict__ out) {
    __shared__ float tile[32][33];
    int kt = blockIdx.x, st = blockIdx.y;
    int bn = blockIdx.z; int b = bn >> 7, n = bn & 127;
    int tx = threadIdx.x & 31, ty = threadIdx.x >> 5;
    const float mu = stats[b * 2], rs = stats[b * 2 + 1];
    const float ga = gg[n] * rs, bb = gb[n];
    const float* fb = f + (long)(b * 250) * 32000 + n * 250;
#pragma unroll
    for (int j = 0; j < 4; ++j) {
        int k = kt * 32 + tx;
        int s = st * 32 + ty + j * 8;
        if (k < 250 && s < 250) tile[ty + j * 8][tx] = fb[(long)s * 32000 + k];
    }
    __syncthreads();
#pragma unroll
    for (int j = 0; j < 4; ++j) {
        int s = st * 32 + tx;
        int k = kt * 32 + ty + j * 8;
        if (k < 250 && s < 250) {
            long idx = ((long)(b * 128 + n) * 250 + k) * 250 + s;
            out[idx] = (tile[tx][ty + j * 8] - mu) * ga + bb + x[idx];
        }
    }
}

// ---------- final: out += GroupNorm(inter) transposed back ----------
__global__ void final_kernel(const float* __restrict__ f2, const float* __restrict__ stats,
                             const float* __restrict__ gg, const float* __restrict__ gb,
                             float* __restrict__ out) {
    long g = (long)blockIdx.x * 256 + threadIdx.x;
    if (g >= NTOT) return;
    int s = (int)(g % 250); long r = g / 250;
    int k = (int)(r % 250); long bn = r / 250;
    int n = (int)(bn % 128); int b = (int)(bn / 128);
    float mu = stats[b * 2], rs = stats[b * 2 + 1];
    float v = f2[((long)(b * 250 + k) * 128 + n) * 250 + s];
    out[g] = (v - mu) * rs * gg[n] + gb[n] + out[g];
}

extern "C" void kernel_launch(void* const* d_in, const int* in_sizes, int n_in,
                              void* d_out, int out_size, void* d_ws, size_t ws_size,
                              hipStream_t stream) {
    (void)in_sizes; (void)n_in; (void)out_size; (void)ws_size;
    const float* x = (const float*)d_in[0];
    float* out = (float*)d_out;
    char* base = (char*)d_ws;
    float* V            = (float*)base;                              // 128,000,000 B
    unsigned short* Ybf = (unsigned short*)(base + 128000000L);      //  64,000,000 B
    float* wC           = (float*)(base + 256000000L);               //      65,536 B
    unsigned short* owbf= (unsigned short*)(base + 256065536L);      //      65,536 B
    unsigned short* lwbf= (unsigned short*)(base + 256131072L);      //      32,768 B
    float* part         = (float*)(base + 256163840L);               //      16,000 B (4000 floats)
    float* stats        = (float*)(base + 256180224L);               //          32 B
    // scratch inside V's region (consumed by conv before mlp writes V):
    float* kern         = (float*)(base + 118000000L);               //     131,072 B
    unsigned short* fragH = (unsigned short*)(base + 120000000L);    //   2,097,152 B
    unsigned short* fragL = (unsigned short*)(base + 123000000L);    //   2,097,152 B

    const float* i_logdt = (const float*)d_in[1];
    const float* i_logA  = (const float*)d_in[2];
    const float* i_Aim   = (const float*)d_in[3];
    const float* i_Cre   = (const float*)d_in[4];
    const float* i_Cim   = (const float*)d_in[5];
    const float* i_D     = (const float*)d_in[6];
    const float* i_ow    = (const float*)d_in[7];
    const float* i_ob    = (const float*)d_in[8];
    const float* i_lw    = (const float*)d_in[9];
    const float* i_lb    = (const float*)d_in[10];
    const float* i_gg    = (const float*)d_in[11];
    const float* i_gb    = (const float*)d_in[12];
    const float* e_logdt = (const float*)d_in[13];
    const float* e_logA  = (const float*)d_in[14];
    const float* e_Aim   = (const float*)d_in[15];
    const float* e_Cre   = (const float*)d_in[16];
    const float* e_Cim   = (const float*)d_in[17];
    const float* e_D     = (const float*)d_in[18];
    const float* e_ow    = (const float*)d_in[19];
    const float* e_ob    = (const float*)d_in[20];
    const float* e_lw    = (const float*)d_in[21];
    const float* e_lb    = (const float*)d_in[22];
    const float* e_gg    = (const float*)d_in[23];
    const float* e_gb    = (const float*)d_in[24];

    // ---- intra path ----
    wc_kernel<<<16, 256, 0, stream>>>(i_logdt, i_logA, i_Aim, i_Cre, i_Cim, wC);
    kern_kernel<<<128, 256, 0, stream>>>(wC, i_D, kern);
    frag_kernel<<<dim3(128, 16), 64, 0, stream>>>(kern, fragH, fragL);
    cvtw_kernel<<<192, 256, 0, stream>>>(i_ow, i_lw, owbf, lwbf);
    conv_kernel<<<dim3(4, 128, 4), 256, 0, stream>>>(x, Ybf, fragH, fragL, 0);
    mlp_kernel<<<dim3(1000, 2), 256, 0, stream>>>(Ybf, owbf, i_ob, lwbf, i_lb, V, part);
    stats_final_kernel<<<4, 256, 0, stream>>>(part, stats);
    intra_fin_kernel<<<dim3(8, 8, 512), 256, 0, stream>>>(V, x, stats, i_gg, i_gb, out);

    // ---- inter path ----
    wc_kernel<<<16, 256, 0, stream>>>(e_logdt, e_logA, e_Aim, e_Cre, e_Cim, wC);
    kern_kernel<<<128, 256, 0, stream>>>(wC, e_D, kern);
    frag_kernel<<<dim3(128, 16), 64, 0, stream>>>(kern, fragH, fragL);
    cvtw_kernel<<<192, 256, 0, stream>>>(e_ow, e_lw, owbf, lwbf);
    conv_kernel<<<dim3(4, 128, 4), 256, 0, stream>>>(out, Ybf, fragH, fragL, 1);
    mlp_kernel<<<dim3(1000, 2), 256, 0, stream>>>(Ybf, owbf, e_ob, lwbf, e_lb, V, part);
    stats_final_kernel<<<4, 256, 0, stream>>>(part, stats);
    final_kernel<<<NTOT / 256, 256, 0, stream>>>(V, stats, e_gg, e_gb, out);
}

// Round 8
// 824.991 us; speedup vs baseline: 1.0841x; 1.0841x over previous
//
#include <hip/hip_runtime.h>
#include <math.h>

#define NTOT 32000000   // 4*128*250*250

typedef __attribute__((ext_vector_type(8))) short bf8_t;   // 8 bf16 (4 VGPRs)
typedef __attribute__((ext_vector_type(4))) float f4_t;    // MFMA accumulator

__device__ __forceinline__ float fast_tanh(float t) {
    return 1.0f - 2.0f / (1.0f + __expf(2.0f * t));
}
__device__ __forceinline__ float gelu_f(float v) {
    return 0.5f * v * (1.0f + fast_tanh(0.7978845608028654f * (v + 0.044715f * v * v * v)));
}
__device__ __forceinline__ float sigmoid_f(float v) {
    return 1.0f / (1.0f + __expf(-v));
}
__device__ __forceinline__ unsigned short f2bf(float f) {
    unsigned u = __float_as_uint(f);
    u = (u + 0x7FFFu + ((u >> 16) & 1u)) >> 16;
    return (unsigned short)u;
}
__device__ __forceinline__ float bf2f(unsigned short u) {
    return __uint_as_float(((unsigned)u) << 16);
}
// packed f32x2 -> bf16x2 (RTNE, same bits as f2bf): D[15:0]=cvt(a), D[31:16]=cvt(b)
__device__ __forceinline__ unsigned cvtpk(float a, float b) {
    unsigned r;
    asm("v_cvt_pk_bf16_f32 %0, %1, %2" : "=v"(r) : "v"(a), "v"(b));
    return r;
}
__device__ __forceinline__ unsigned swz(unsigned a) {   // flat-byte XOR swizzle (mlp ZL)
    return a ^ (((a >> 9) & 7u) << 4);
}
// row XOR swizzle: ONLY valid for row pitches that are multiples of 128 B
__device__ __forceinline__ unsigned fxor(int row) {
    return ((unsigned)(row & 1) << 6) ^ ((unsigned)((row >> 1) & 7) << 4);
}

// ---------- S4D discretization: store dt*Re(A), dt*Im(A), 2*C' ----------
__global__ void wc_kernel(const float* __restrict__ log_dt, const float* __restrict__ logA_re,
                          const float* __restrict__ A_im, const float* __restrict__ C_re,
                          const float* __restrict__ C_im, float* __restrict__ wC) {
    int t = blockIdx.x * 256 + threadIdx.x;
    if (t >= 128 * 32) return;
    int h = t >> 5, m = t & 31;
    float dt  = expf(log_dt[h]);
    float are = -expf(logA_re[t]);
    float aim = A_im[t];
    float er  = expf(dt * are);
    float wr  = er * cosf(dt * aim);
    float wi  = er * sinf(dt * aim);
    float e1r = wr - 1.0f, e1i = wi;
    float inv = 1.0f / (are * are + aim * aim);
    float qr  = (e1r * are + e1i * aim) * inv;
    float qi  = (e1i * are - e1r * aim) * inv;
    float cre = C_re[t], cim = C_im[t];
    wC[h * 128 + m]      = dt * are;
    wC[h * 128 + 32 + m] = dt * aim;
    wC[h * 128 + 64 + m] = 2.0f * (cre * qr - cim * qi);
    wC[h * 128 + 96 + m] = 2.0f * (cre * qi + cim * qr);
}

// ---------- conv kernel taps: kern[h][l] = 2*Re(sum_m C'_m exp(dtA_m*l)) + D[h]*(l==0) ----------
__global__ void kern_kernel(const float* __restrict__ wC, const float* __restrict__ Dv,
                            float* __restrict__ kern) {
    int h = blockIdx.x, l = threadIdx.x;
    const float* wc = wC + (h << 7);
    float acc = 0.0f;
    if (l < 250) {
        float fl = (float)l;
#pragma unroll 1
        for (int m = 0; m < 32; ++m) {
            float er  = expf(wc[m] * fl);
            float ang = wc[32 + m] * fl;
            float sv, cv;
            sincosf(ang, &sv, &cv);
            acc += er * (wc[64 + m] * cv - wc[96 + m] * sv);
        }
        if (l == 0) acc += Dv[h];
    }
    kern[(h << 8) + l] = acc;
}

// ---------- Toeplitz A-fragments (hi/lo bf16) per (h, diag16, lane) ----------
__global__ void frag_kernel(const float* __restrict__ kern, unsigned short* __restrict__ fragH,
                            unsigned short* __restrict__ fragL) {
    int h = blockIdx.x, d16 = blockIdx.y, lane = threadIdx.x;
    int lid = lane & 15, q = lane >> 4;
    const float* kh = kern + (h << 8);
    bf8_t vh, vl;
#pragma unroll
    for (int j = 0; j < 8; ++j) {
        int idx = d16 * 16 + lid - 8 * q - j;
        float v = (idx >= 0) ? kh[idx] : 0.0f;
        unsigned short hb = f2bf(v);
        vh[j] = (short)hb;
        vl[j] = (short)f2bf(v - bf2f(hb));
    }
    long off = ((long)((h << 4) + d16) * 64 + lane) * 8;
    *(bf8_t*)(fragH + off) = vh;
    *(bf8_t*)(fragL + off) = vl;
}

// ---------- weight fp32 -> bf16 ----------
__global__ void cvtw_kernel(const float* __restrict__ ow, const float* __restrict__ lw,
                            unsigned short* __restrict__ owbf, unsigned short* __restrict__ lwbf) {
    int t = blockIdx.x * 256 + threadIdx.x;
    if (t < 32768) owbf[t] = f2bf(ow[t]);
    else if (t < 49152) lwbf[t - 32768] = f2bf(lw[t - 32768]);
}

// ---------- causal S4D conv as Toeplitz MFMA GEMM (bf16x3 ~ fp32) + GELU -> bf16 Y ----------
// 8-wave (512-thread) blocks: 2 blocks/CU x 8 waves = 16 waves/CU (4/SIMD) vs 3/SIMD before.
// Balanced row-tile pairing r in {w, 15-w}: every wave has exactly 9 active causal (r,c) slots.
// Per-chunk pipelined staging (R6 structure) + cvtpk conversions. 40 KB LDS.
__global__ __launch_bounds__(512, 4)
void conv_kernel(const float* __restrict__ in, unsigned short* __restrict__ Y,
                 const unsigned short* __restrict__ fragH, const unsigned short* __restrict__ fragL,
                 int inter) {
    __shared__ unsigned short Bhi[64 * 256];   // [seq][k] hi bf16, 512B rows, fxor-swizzled (32 KB)
    __shared__ unsigned short Blo[64 * 64];    // [seq][k-chunk] lo bf16, 128B rows, fxor-swizzled (8 KB)
    const int tid = threadIdx.x;
    const int lane = tid & 63, wave = tid >> 6;    // wave 0..7
    const int lid = lane & 15, quad = lane >> 4;
    const int s0 = blockIdx.x * 64;
    const int h = blockIdx.y, b = blockIdx.z;
    const float* src = in + (long)(b * 128 + h) * 62500;
    char* BhiB = (char*)Bhi;
    char* BloB = (char*)Blo;
    const int r0 = wave;          // row16-tile pair (balanced causal work)
    const int r1 = 15 - wave;
    const int kk2 = tid >> 5;           // 0..15 (intra k-pair group)
    const int sp  = (tid & 31) << 1;    // 0..62 (even seq row)

    f4_t acc[2][4];
#pragma unroll
    for (int ri = 0; ri < 2; ++ri)
#pragma unroll
        for (int ct = 0; ct < 4; ++ct) acc[ri][ct] = (f4_t)0.0f;

    float2 pv[2];
    auto loadc = [&](int c) {
        if (!inter) {
#pragma unroll
            for (int it = 0; it < 2; ++it) {
                int k = (c << 5) + kk2 * 2 + it;
                bool ok = (k < 250) && (s0 + sp < 250);
                pv[it] = ok ? *(const float2*)(src + (long)k * 250 + s0 + sp)
                            : make_float2(0.0f, 0.0f);
            }
        } else {
#pragma unroll
            for (int it = 0; it < 2; ++it) {
                int i = tid + (it << 9);
                int sq = i >> 4;
                int tt = (i & 15) << 1;
                int t = (c << 5) + tt;
                bool ok = (s0 + sq < 250) && (t < 250);
                pv[it] = ok ? *(const float2*)(src + (long)(s0 + sq) * 250 + t)
                            : make_float2(0.0f, 0.0f);
            }
        }
    };
    auto storec = [&](int c) {
        if (!inter) {
            // thread holds k-pair (kk2*2, kk2*2+1) at rows sp, sp+1 -> 2 hi u32 + 2 lo u32
            unsigned h0 = cvtpk(pv[0].x, pv[1].x);
            unsigned h1 = cvtpk(pv[0].y, pv[1].y);
            unsigned l0v = cvtpk(pv[0].x - __uint_as_float(h0 << 16),
                                 pv[1].x - __uint_as_float(h0 & 0xFFFF0000u));
            unsigned l1v = cvtpk(pv[0].y - __uint_as_float(h1 << 16),
                                 pv[1].y - __uint_as_float(h1 & 0xFFFF0000u));
            unsigned colH = (unsigned)((c << 6) + (kk2 << 2));
            *(unsigned*)(BhiB + (((unsigned)(sp * 512) + colH) ^ fxor(sp)));
            *(unsigned*)(BhiB + (((unsigned)(sp * 512) + colH) ^ fxor(sp))) = h0;
            *(unsigned*)(BhiB + (((unsigned)((sp + 1) * 512) + colH) ^ fxor(sp + 1))) = h1;
            unsigned colL = (unsigned)(kk2 << 2);
            *(unsigned*)(BloB + (((unsigned)(sp * 128) + colL) ^ fxor(sp))) = l0v;
            *(unsigned*)(BloB + (((unsigned)((sp + 1) * 128) + colL) ^ fxor(sp + 1))) = l1v;
        } else {
#pragma unroll
            for (int it = 0; it < 2; ++it) {
                int i = tid + (it << 9);
                int sq = i >> 4;
                int tt = (i & 15) << 1;
                int t = (c << 5) + tt;
                unsigned hp = cvtpk(pv[it].x, pv[it].y);
                unsigned lp = cvtpk(pv[it].x - __uint_as_float(hp << 16),
                                    pv[it].y - __uint_as_float(hp & 0xFFFF0000u));
                *(unsigned*)(BhiB + (((unsigned)(sq * 512 + t * 2)) ^ fxor(sq))) = hp;
                *(unsigned*)(BloB + (((unsigned)(sq * 128 + tt * 2)) ^ fxor(sq))) = lp;
            }
        }
    };

    loadc(0);
#pragma unroll 1
    for (int c = 0; c < 8; ++c) {
        __syncthreads();           // prev chunk's B-reads done
        storec(c);
        __syncthreads();           // staging visible
        if (c < 7) loadc(c + 1);   // prefetch under MFMAs
        bf8_t bh[4], bl[4];
#pragma unroll
        for (int ct = 0; ct < 4; ++ct) {
            int row = ct * 16 + lid;
            bh[ct] = *(const bf8_t*)(BhiB + (((unsigned)(row * 512 + c * 64 + quad * 16)) ^ fxor(row)));
            bl[ct] = *(const bf8_t*)(BloB + (((unsigned)(row * 128 + quad * 16)) ^ fxor(row)));
        }
#pragma unroll
        for (int ri = 0; ri < 2; ++ri) {
            int r = ri ? r1 : r0;
            if (r >= 2 * c) {           // causal: A-tile [16r,16r+16) x [32c,32c+32) nonzero
                long fo = ((long)((h << 4) + (r - 2 * c)) * 64 + lane) * 8;
                bf8_t fh = *(const bf8_t*)(fragH + fo);
                bf8_t fl = *(const bf8_t*)(fragL + fo);
#pragma unroll
                for (int ct = 0; ct < 4; ++ct) {
                    acc[ri][ct] = __builtin_amdgcn_mfma_f32_16x16x32_bf16(fh, bh[ct], acc[ri][ct], 0, 0, 0);
                    acc[ri][ct] = __builtin_amdgcn_mfma_f32_16x16x32_bf16(fh, bl[ct], acc[ri][ct], 0, 0, 0);
                    acc[ri][ct] = __builtin_amdgcn_mfma_f32_16x16x32_bf16(fl, bh[ct], acc[ri][ct], 0, 0, 0);
                }
            }
        }
    }
    __syncthreads();   // all B-reads done before epilogue overwrites Bhi
    // epilogue: gelu(acc) -> Bhi[seq][l] bf16 (packed 8B writes)
#pragma unroll
    for (int ri = 0; ri < 2; ++ri) {
        const int r = ri ? r1 : r0;
        const int l0 = r * 16 + quad * 4;
#pragma unroll
        for (int ct = 0; ct < 4; ++ct) {
            const int sq = ct * 16 + lid;
            unsigned lo = cvtpk(gelu_f(acc[ri][ct][0]), gelu_f(acc[ri][ct][1]));
            unsigned hi = cvtpk(gelu_f(acc[ri][ct][2]), gelu_f(acc[ri][ct][3]));
            unsigned byteO = ((unsigned)(sq * 512 + l0 * 2)) ^ fxor(sq);
            *(uint2*)(BhiB + byteO) = make_uint2(lo, hi);
        }
    }
    __syncthreads();
    // coalesced copy-out: Y[(b*250+s0+sq)*128 + h][l], 250 bf16 = 125 u32 per row
    unsigned int* Yg = (unsigned int*)Y + ((long)(b * 250 + s0) * 128 + h) * 125;
#pragma unroll 1
    for (int i = tid; i < 8192; i += 512) {
        int sq = i >> 7, e = i & 127;
        if (e < 125 && s0 + sq < 250) {
            unsigned v = *(unsigned*)(BhiB + (((unsigned)(sq * 512 + e * 4)) ^ fxor(sq)));
            Yg[(long)sq * 16000 + e] = v;
        }
    }
}

// ---------- fused MLP (half-seq blocks): GEMM1+GLU -> flat LDS -> GEMM2 -> V + GN partials ----------
// Exact split: flat rows [0,125) use h<64, rows [125,250) use h>=64 (125*128 == 64*250).
__global__ __launch_bounds__(256, 3)
void mlp_kernel(const unsigned short* __restrict__ Ybf, const unsigned short* __restrict__ owbf,
                const float* __restrict__ ob, const unsigned short* __restrict__ lwbf,
                const float* __restrict__ lb, float* __restrict__ V, float* __restrict__ part) {
    __shared__ unsigned short ZL[16000];     // 32 KB: local flat bf16 (h'*250+l)*2 ^ swz
    __shared__ unsigned short Yt[32 * 128];  // chunk transpose [l(32)][h(128)], 256B rows, fxor'd
    const int tid = threadIdx.x;
    const int lane = tid & 63, wave = tid >> 6;
    const int lid = lane & 15, quad = lane >> 4;
    const int seq = blockIdx.x, hf = blockIdx.y;
    const unsigned short* Ys = Ybf + (long)seq * 32000;
    char* YtB = (char*)Yt;
    char* ZLB = (char*)ZL;

    const int tA = 4 * hf + wave;        // z1 tile
    const int tB = 8 + 4 * hf + wave;    // z2 tile
    bf8_t wf[4][2];
#pragma unroll
    for (int c = 0; c < 4; ++c) {
        wf[c][0] = *(const bf8_t*)(owbf + (tA * 16 + lid) * 128 + c * 32 + quad * 8);
        wf[c][1] = *(const bf8_t*)(owbf + (tB * 16 + lid) * 128 + c * 32 + quad * 8);
    }
    float ob1[4], ob2[4];
#pragma unroll
    for (int reg = 0; reg < 4; ++reg) {
        int hp = wave * 16 + quad * 4 + reg;    // local h' in [0,64)
        ob1[reg] = ob[64 * hf + hp];
        ob2[reg] = ob[128 + 64 * hf + hp];
    }

    unsigned int pf[8];
    auto loadc = [&](int l0) {
#pragma unroll
        for (int it = 0; it < 8; ++it) {
            int i = tid + it * 256;
            int hh = i >> 4;
            int l = l0 + (i & 15) * 2;
            pf[it] = (l < 250) ? *(const unsigned int*)(Ys + hh * 250 + l) : 0u;
        }
    };
    auto storec = [&]() {
#pragma unroll
        for (int it = 0; it < 8; ++it) {
            int i = tid + it * 256;
            int hh = i >> 4;
            int l2 = (i & 15) * 2;
            unsigned a0 = ((unsigned)(l2 * 256 + hh * 2)) ^ fxor(l2);
            unsigned a1 = ((unsigned)((l2 + 1) * 256 + hh * 2)) ^ fxor(l2 + 1);
            *(unsigned short*)(YtB + a0) = (unsigned short)(pf[it] & 0xFFFF);
            *(unsigned short*)(YtB + a1) = (unsigned short)(pf[it] >> 16);
        }
    };

    loadc(0);
#pragma unroll 1
    for (int ch = 0; ch < 8; ++ch) {
        __syncthreads();
        storec();
        __syncthreads();
        if (ch < 7) loadc((ch + 1) * 32);
        f4_t acc[2][2];
#pragma unroll
        for (int pp = 0; pp < 2; ++pp)
#pragma unroll
            for (int jj = 0; jj < 2; ++jj) acc[pp][jj] = (f4_t)0.0f;
#pragma unroll
        for (int c = 0; c < 4; ++c) {
            bf8_t bfr[2];
#pragma unroll
            for (int jj = 0; jj < 2; ++jj) {
                int row = jj * 16 + lid;
                bfr[jj] = *(const bf8_t*)(YtB + (((unsigned)(row * 256 + c * 64 + quad * 16)) ^ fxor(row)));
            }
#pragma unroll
            for (int pp = 0; pp < 2; ++pp)
#pragma unroll
                for (int jj = 0; jj < 2; ++jj)
                    acc[pp][jj] = __builtin_amdgcn_mfma_f32_16x16x32_bf16(wf[c][pp], bfr[jj], acc[pp][jj], 0, 0, 0);
        }
        const int lbase = ch * 32;
#pragma unroll
        for (int reg = 0; reg < 4; ++reg) {
            int hp = wave * 16 + quad * 4 + reg;
#pragma unroll
            for (int jj = 0; jj < 2; ++jj) {
                int l = lbase + jj * 16 + lid;
                if (l < 250) {
                    float z1 = acc[0][jj][reg] + ob1[reg];
                    float z2 = acc[1][jj][reg] + ob2[reg];
                    unsigned aB = swz((unsigned)(hp * 250 + l) * 2u);
                    *(unsigned short*)(ZLB + aB) = f2bf(z1 * sigmoid_f(z2));
                }
            }
        }
    }
    __syncthreads();

    // GEMM2: 4 waves x 32 local flat rows (125 valid)
    f4_t acc2[2][8];
#pragma unroll
    for (int mt = 0; mt < 2; ++mt)
#pragma unroll
        for (int nt = 0; nt < 8; ++nt) acc2[mt][nt] = (f4_t)0.0f;
    const int jl0 = wave * 32;
#pragma unroll
    for (int c = 0; c < 4; ++c) {
        bf8_t af[2];
#pragma unroll
        for (int mt = 0; mt < 2; ++mt) {
            int jl = jl0 + mt * 16 + lid;
            if (jl > 124) jl = 124;
            af[mt] = *(const bf8_t*)(ZLB + swz((unsigned)(jl * 128 + c * 32 + quad * 8) * 2u));
        }
#pragma unroll
        for (int nt = 0; nt < 8; ++nt) {
            bf8_t bfr = *(const bf8_t*)(lwbf + (nt * 16 + lid) * 128 + c * 32 + quad * 8);
#pragma unroll
            for (int mt = 0; mt < 2; ++mt)
                acc2[mt][nt] = __builtin_amdgcn_mfma_f32_16x16x32_bf16(af[mt], bfr, acc2[mt][nt], 0, 0, 0);
        }
    }
    float s = 0.0f, q = 0.0f;
    float* Vs = V + (long)seq * 32000 + hf * 16000;
#pragma unroll
    for (int nt = 0; nt < 8; ++nt) {
        int o = nt * 16 + lid;
        float bb = lb[o];
#pragma unroll
        for (int mt = 0; mt < 2; ++mt)
#pragma unroll
            for (int reg = 0; reg < 4; ++reg) {
                int jlr = jl0 + mt * 16 + quad * 4 + reg;
                if (jlr < 125) {
                    float v = acc2[mt][nt][reg] + bb;
                    Vs[jlr * 128 + o] = v;
                    s += v;
                    q += v * v;
                }
            }
    }
    __syncthreads();
    float* red = (float*)Yt;
    red[tid] = s;
    red[256 + tid] = q;
    __syncthreads();
    for (int st = 128; st > 0; st >>= 1) {
        if (tid < st) {
            red[tid] += red[tid + st];
            red[256 + tid] += red[256 + tid + st];
        }
        __syncthreads();
    }
    if (tid == 0) {
        part[(seq * 2 + hf) * 2]     = red[0];
        part[(seq * 2 + hf) * 2 + 1] = red[256];
    }
}

// ---------- reduce per-(seq,half) partials (500 per batch) -> mean, rstd ----------
__global__ void stats_final_kernel(const float* __restrict__ part, float* __restrict__ stats) {
    __shared__ double ssum[256], ssq[256];
    const int b = blockIdx.x;
    double s = 0.0, q = 0.0;
    for (int i = threadIdx.x; i < 500; i += 256) {
        s += (double)part[(b * 500 + i) * 2];
        q += (double)part[(b * 500 + i) * 2 + 1];
    }
    ssum[threadIdx.x] = s; ssq[threadIdx.x] = q;
    __syncthreads();
    for (int st = 128; st > 0; st >>= 1) {
        if (threadIdx.x < st) {
            ssum[threadIdx.x] += ssum[threadIdx.x + st];
            ssq[threadIdx.x]  += ssq[threadIdx.x + st];
        }
        __syncthreads();
    }
    if (threadIdx.x == 0) {
        double mu = ssum[0] / 8000000.0;
        double var = ssq[0] / 8000000.0 - mu * mu;
        stats[b * 2] = (float)mu;
        stats[b * 2 + 1] = (float)(1.0 / sqrt(var + 1e-8));
    }
}

// ---------- intra finalize: transpose-back + GN affine + residual x -> out[B,N,K,S] ----------
__global__ void intra_fin_kernel(const float* __restrict__ f, const float* __restrict__ x,
                                 const float* __restrict__ stats, const float* __restrict__ gg,
                                 const float* __restrict__ gb, float* __restrict__ out) {
    __shared__ float tile[32][33];
    int kt = blockIdx.x, st = blockIdx.y;
    int bn = blockIdx.z; int b = bn >> 7, n = bn & 127;
    int tx = threadIdx.x & 31, ty = threadIdx.x >> 5;
    const float mu = stats[b * 2], rs = stats[b * 2 + 1];
    const float ga = gg[n] * rs, bb = gb[n];
    const float* fb = f + (long)(b * 250) * 32000 + n * 250;
#pragma unroll
    for (int j = 0; j < 4; ++j) {
        int k = kt * 32 + tx;
        int s = st * 32 + ty + j * 8;
        if (k < 250 && s < 250) tile[ty + j * 8][tx] = fb[(long)s * 32000 + k];
    }
    __syncthreads();
#pragma unroll
    for (int j = 0; j < 4; ++j) {
        int s = st * 32 + tx;
        int k = kt * 32 + ty + j * 8;
        if (k < 250 && s < 250) {
            long idx = ((long)(b * 128 + n) * 250 + k) * 250 + s;
            out[idx] = (tile[tx][ty + j * 8] - mu) * ga + bb + x[idx];
        }
    }
}

// ---------- final: out += GroupNorm(inter) transposed back ----------
__global__ void final_kernel(const float* __restrict__ f2, const float* __restrict__ stats,
                             const float* __restrict__ gg, const float* __restrict__ gb,
                             float* __restrict__ out) {
    long g = (long)blockIdx.x * 256 + threadIdx.x;
    if (g >= NTOT) return;
    int s = (int)(g % 250); long r = g / 250;
    int k = (int)(r % 250); long bn = r / 250;
    int n = (int)(bn % 128); int b = (int)(bn / 128);
    float mu = stats[b * 2], rs = stats[b * 2 + 1];
    float v = f2[((long)(b * 250 + k) * 128 + n) * 250 + s];
    out[g] = (v - mu) * rs * gg[n] + gb[n] + out[g];
}

extern "C" void kernel_launch(void* const* d_in, const int* in_sizes, int n_in,
                              void* d_out, int out_size, void* d_ws, size_t ws_size,
                              hipStream_t stream) {
    (void)in_sizes; (void)n_in; (void)out_size; (void)ws_size;
    const float* x = (const float*)d_in[0];
    float* out = (float*)d_out;
    char* base = (char*)d_ws;
    float* V            = (float*)base;                              // 128,000,000 B
    unsigned short* Ybf = (unsigned short*)(base + 128000000L);      //  64,000,000 B
    float* wC           = (float*)(base + 256000000L);               //      65,536 B
    unsigned short* owbf= (unsigned short*)(base + 256065536L);      //      65,536 B
    unsigned short* lwbf= (unsigned short*)(base + 256131072L);      //      32,768 B
    float* part         = (float*)(base + 256163840L);               //      16,000 B (4000 floats)
    float* stats        = (float*)(base + 256180224L);               //          32 B
    // scratch inside V's region (consumed by conv before mlp writes V):
    float* kern         = (float*)(base + 118000000L);               //     131,072 B
    unsigned short* fragH = (unsigned short*)(base + 120000000L);    //   2,097,152 B
    unsigned short* fragL = (unsigned short*)(base + 123000000L);    //   2,097,152 B

    const float* i_logdt = (const float*)d_in[1];
    const float* i_logA  = (const float*)d_in[2];
    const float* i_Aim   = (const float*)d_in[3];
    const float* i_Cre   = (const float*)d_in[4];
    const float* i_Cim   = (const float*)d_in[5];
    const float* i_D     = (const float*)d_in[6];
    const float* i_ow    = (const float*)d_in[7];
    const float* i_ob    = (const float*)d_in[8];
    const float* i_lw    = (const float*)d_in[9];
    const float* i_lb    = (const float*)d_in[10];
    const float* i_gg    = (const float*)d_in[11];
    const float* i_gb    = (const float*)d_in[12];
    const float* e_logdt = (const float*)d_in[13];
    const float* e_logA  = (const float*)d_in[14];
    const float* e_Aim   = (const float*)d_in[15];
    const float* e_Cre   = (const float*)d_in[16];
    const float* e_Cim   = (const float*)d_in[17];
    const float* e_D     = (const float*)d_in[18];
    const float* e_ow    = (const float*)d_in[19];
    const float* e_ob    = (const float*)d_in[20];
    const float* e_lw    = (const float*)d_in[21];
    const float* e_lb    = (const float*)d_in[22];
    const float* e_gg    = (const float*)d_in[23];
    const float* e_gb    = (const float*)d_in[24];

    // ---- intra path ----
    wc_kernel<<<16, 256, 0, stream>>>(i_logdt, i_logA, i_Aim, i_Cre, i_Cim, wC);
    kern_kernel<<<128, 256, 0, stream>>>(wC, i_D, kern);
    frag_kernel<<<dim3(128, 16), 64, 0, stream>>>(kern, fragH, fragL);
    cvtw_kernel<<<192, 256, 0, stream>>>(i_ow, i_lw, owbf, lwbf);
    conv_kernel<<<dim3(4, 128, 4), 512, 0, stream>>>(x, Ybf, fragH, fragL, 0);
    mlp_kernel<<<dim3(1000, 2), 256, 0, stream>>>(Ybf, owbf, i_ob, lwbf, i_lb, V, part);
    stats_final_kernel<<<4, 256, 0, stream>>>(part, stats);
    intra_fin_kernel<<<dim3(8, 8, 512), 256, 0, stream>>>(V, x, stats, i_gg, i_gb, out);

    // ---- inter path ----
    wc_kernel<<<16, 256, 0, stream>>>(e_logdt, e_logA, e_Aim, e_Cre, e_Cim, wC);
    kern_kernel<<<128, 256, 0, stream>>>(wC, e_D, kern);
    frag_kernel<<<dim3(128, 16), 64, 0, stream>>>(kern, fragH, fragL);
    cvtw_kernel<<<192, 256, 0, stream>>>(e_ow, e_lw, owbf, lwbf);
    conv_kernel<<<dim3(4, 128, 4), 512, 0, stream>>>(out, Ybf, fragH, fragL, 1);
    mlp_kernel<<<dim3(1000, 2), 256, 0, stream>>>(Ybf, owbf, e_ob, lwbf, e_lb, V, part);
    stats_final_kernel<<<4, 256, 0, stream>>>(part, stats);
    final_kernel<<<NTOT / 256, 256, 0, stream>>>(V, stats, e_gg, e_gb, out);
}